// Round 4
// baseline (350.510 us; speedup 1.0000x reference)
//
#include <hip/hip_runtime.h>
#include <math.h>

// Problem constants (fixed by the reference)
constexpr int NG    = 128;          // graphs
constexpr int NP    = 1024;         // nodes per graph
constexpr int D     = 256;          // feature dim
constexpr int NTOT  = NG * NP;      // 131072 nodes
constexpr int EPG   = NP * 32;      // 32768 edges per graph (contiguous slice)
constexpr int ET    = NTOT * 32;    // 4194304 edges
constexpr int KK    = 820;          // kept per graph
constexpr int NKEEP = NG * KK;      // 104960 kept nodes
constexpr int BPG   = 4;            // edge slices per graph (K3 edge remap)
constexpr int EPB   = EPG / BPG;    // 8192 edges per slice
constexpr int NBE   = NG * BPG;     // 512 edge slices total

// Grid geometry
constexpr int K1_BLOCKS = 2048;     // 8192 waves, 16 rows/wave
constexpr int K3_BLOCKS = 2048;     // 512 edge blocks + 1536 gather blocks

// Native clang vector type: __builtin_nontemporal_store rejects HIP float4
typedef float v4f __attribute__((ext_vector_type(4)));

// Output layout (flat float32, reference return order)
constexpr long long OUT_X     = 0;
constexpr long long OUT_EI0   = (long long)NKEEP * D;     // 26869760
constexpr long long OUT_EI1   = OUT_EI0 + ET;
constexpr long long OUT_MASK  = OUT_EI0 + 2LL * ET;
constexpr long long OUT_BATCH = OUT_MASK + ET;
constexpr long long OUT_PERM  = OUT_BATCH + NKEEP;        // total 39662592

// ---------------------------------------------------------------------------
// K1: h[i] = dot(x[i,:], W) (wave-per-row, float4, unroll-4 for ILP)
//     + new_id = -1. 2048 blocks x 256 -> 32 waves/CU, pure streaming.
__global__ __launch_bounds__(256) void k1_h(const float* __restrict__ x,
                                            const float* __restrict__ W,
                                            float* __restrict__ h,
                                            int* __restrict__ new_id) {
    const int t    = threadIdx.x;
    const int w    = t >> 6;
    const int lane = t & 63;
    const int gw   = blockIdx.x * 4 + w;            // 0..8191, 16 rows each

    float4 w4 = ((const float4*)W)[lane];
    const float4* xp = (const float4*)(x + (size_t)gw * 16 * D);

#pragma unroll
    for (int c = 0; c < 4; ++c) {
        // 4 independent row loads in flight
        float4 a0 = xp[(c * 4 + 0) * 64 + lane];
        float4 a1 = xp[(c * 4 + 1) * 64 + lane];
        float4 a2 = xp[(c * 4 + 2) * 64 + lane];
        float4 a3 = xp[(c * 4 + 3) * 64 + lane];
        float s0 = a0.x * w4.x + a0.y * w4.y + a0.z * w4.z + a0.w * w4.w;
        float s1 = a1.x * w4.x + a1.y * w4.y + a1.z * w4.z + a1.w * w4.w;
        float s2 = a2.x * w4.x + a2.y * w4.y + a2.z * w4.z + a2.w * w4.w;
        float s3 = a3.x * w4.x + a3.y * w4.y + a3.z * w4.z + a3.w * w4.w;
#pragma unroll
        for (int off = 32; off > 0; off >>= 1) {    // 4 interleaved chains
            s0 += __shfl_down(s0, off, 64);
            s1 += __shfl_down(s1, off, 64);
            s2 += __shfl_down(s2, off, 64);
            s3 += __shfl_down(s3, off, 64);
        }
        if (lane == 0) {
            const int r = gw * 16 + c * 4;
            h[r] = s0; h[r + 1] = s1; h[r + 2] = s2; h[r + 3] = s3;
            new_id[r]     = -1; new_id[r + 1] = -1;
            new_id[r + 2] = -1; new_id[r + 3] = -1;
        }
    }
}

// ---------------------------------------------------------------------------
// K2: one 1024-thread block per graph does the whole graph-local pipeline:
//     deg (LDS atomics) -> u = rsqrt(deg)*h -> acc[c] += u[r] (LDS atomics)
//     -> score -> register bitonic top-k -> epilogue.
//     Thread t owns node t exactly (NP == 1024). No global partial buffers.
//     LDS: sk 8KB (aliased: cnt int[1024] | ul float[1024]) + acc 4KB + scl 4KB.
__global__ __launch_bounds__(1024) void k2_graph(
        const float* __restrict__ h,  const float* __restrict__ bptr,
        const int* __restrict__ rows, const int* __restrict__ cols,
        int* __restrict__ perm_i,     int* __restrict__ new_id,
        float* __restrict__ factor,
        float* __restrict__ out_perm, float* __restrict__ out_batch) {
    __shared__ unsigned long long sk[NP];   // sort buffer; aliases cnt & ul
    __shared__ float acc[NP];
    __shared__ float scl[NP];
    int*   cnt = (int*)sk;                  // bytes [0, 4K)
    float* ul  = (float*)sk + NP;           // bytes [4K, 8K)

    const int g = blockIdx.x;
    const int t = threadIdx.x;

    const float hv = h[g * NP + t];
    cnt[t] = 0;
    __syncthreads();

    const int4* c4 = (const int4*)(cols + (size_t)g * EPG);
    const int4* r4 = (const int4*)(rows + (size_t)g * EPG);

    // degree: 32768 target counts via privatized LDS atomics
#pragma unroll
    for (int i = t; i < EPG / 4; i += 1024) {        // 8 iters
        int4 c = c4[i];
        atomicAdd(&cnt[c.x & (NP - 1)], 1);
        atomicAdd(&cnt[c.y & (NP - 1)], 1);
        atomicAdd(&cnt[c.z & (NP - 1)], 1);
        atomicAdd(&cnt[c.w & (NP - 1)], 1);
    }
    __syncthreads();

    const float di = rsqrtf((float)(1 + cnt[t]));    // self-loop included
    ul[t]  = di * hv;
    acc[t] = 0.0f;
    __syncthreads();

    // aggregation: acc[c] += u[r]  (cols second read should L2-hit)
#pragma unroll
    for (int i = t; i < EPG / 4; i += 1024) {        // 8 iters
        int4 c = c4[i];
        int4 r = r4[i];
        atomicAdd(&acc[c.x & (NP - 1)], ul[r.x & (NP - 1)]);
        atomicAdd(&acc[c.y & (NP - 1)], ul[r.y & (NP - 1)]);
        atomicAdd(&acc[c.z & (NP - 1)], ul[r.z & (NP - 1)]);
        atomicAdd(&acc[c.w & (NP - 1)], ul[r.w & (NP - 1)]);
    }
    __syncthreads();

    const float score = di * acc[t] + di * di * hv + bptr[0];
    scl[t] = score;

    // sortable key: ascending u64 == (descending score, ascending idx)
    unsigned int fu = __float_as_uint(score);
    unsigned int s  = (fu & 0x80000000u) ? ~fu : (fu | 0x80000000u);
    unsigned long long key = ((unsigned long long)(~s) << 32) | (unsigned int)t;
    // cnt/ul reads are done (di, ul consumed before the last barrier), so sk
    // may be overwritten by the sort's LDS stages below.

    for (int k = 2; k <= NP; k <<= 1) {
        for (int j = k >> 1; j > 0; j >>= 1) {
            unsigned long long other;
            if (j < 64) {
                other = __shfl_xor(key, j, 64);
            } else {
                sk[t] = key;
                __syncthreads();
                other = sk[t ^ j];
                __syncthreads();
            }
            bool take_min = (((t & k) == 0) == ((t & j) == 0));
            bool omin = other < key;
            key = (take_min == omin) ? other : key;
        }
    }
    // sort's internal barriers ordered scl[] writes before the reads below

    if (t < KK) {
        int idx  = (int)(key & 0xFFFFFFFFull);
        int node = g * NP + idx;
        int j    = g * KK + t;
        perm_i[j]    = node;
        new_id[node] = j;
        out_perm[j]  = (float)node;
        out_batch[j] = (float)g;         // graphs contiguous: batch[node] == g
        factor[j]    = tanhf(scl[idx]);  // gather scale, precomputed
    }
}

// ---------------------------------------------------------------------------
// K3: gather + edge remap, disjoint block roles for balance.
//     Blocks 0..511: remap one 8192-edge slice (new_id slice staged in LDS).
//     Blocks 512..2047: wave-per-row gather over NKEEP rows.
//     All output stores nontemporal: keep x resident in L3 for the gather.
__global__ __launch_bounds__(256) void k3_gather_edge(
        const float* __restrict__ x,
        const int* __restrict__ rows, const int* __restrict__ cols,
        const int* __restrict__ new_id,
        const int* __restrict__ perm_i, const float* __restrict__ factor,
        float* __restrict__ out) {
    __shared__ int nid[NP];
    const int b    = blockIdx.x;
    const int t    = threadIdx.x;
    const int w    = t >> 6;
    const int lane = t & 63;

    if (b < NBE) {
        const int g = b >> 2;
        for (int i = t; i < NP; i += 256) nid[i] = new_id[g * NP + i];
        __syncthreads();
        size_t eoff = (size_t)g * EPG + (size_t)(b & 3) * EPB;
        const int4* r4 = (const int4*)(rows + eoff);
        const int4* c4 = (const int4*)(cols + eoff);
        v4f* orr = (v4f*)(out + OUT_EI0  + eoff);
        v4f* occ = (v4f*)(out + OUT_EI1  + eoff);
        v4f* omm = (v4f*)(out + OUT_MASK + eoff);
#pragma unroll
        for (int i = t; i < EPB / 4; i += 256) {   // 8 iters
            int4 r = r4[i];
            int4 c = c4[i];
            v4f fr, fc, fm;
            {
                int nr = nid[r.x & (NP - 1)], nc = nid[c.x & (NP - 1)];
                bool m = (nr >= 0) && (nc >= 0);
                fr.x = m ? (float)nr : -1.0f; fc.x = m ? (float)nc : -1.0f; fm.x = m ? 1.0f : 0.0f;
            }
            {
                int nr = nid[r.y & (NP - 1)], nc = nid[c.y & (NP - 1)];
                bool m = (nr >= 0) && (nc >= 0);
                fr.y = m ? (float)nr : -1.0f; fc.y = m ? (float)nc : -1.0f; fm.y = m ? 1.0f : 0.0f;
            }
            {
                int nr = nid[r.z & (NP - 1)], nc = nid[c.z & (NP - 1)];
                bool m = (nr >= 0) && (nc >= 0);
                fr.z = m ? (float)nr : -1.0f; fc.z = m ? (float)nc : -1.0f; fm.z = m ? 1.0f : 0.0f;
            }
            {
                int nr = nid[r.w & (NP - 1)], nc = nid[c.w & (NP - 1)];
                bool m = (nr >= 0) && (nc >= 0);
                fr.w = m ? (float)nr : -1.0f; fc.w = m ? (float)nc : -1.0f; fm.w = m ? 1.0f : 0.0f;
            }
            __builtin_nontemporal_store(fr, &orr[i]);
            __builtin_nontemporal_store(fc, &occ[i]);
            __builtin_nontemporal_store(fm, &omm[i]);
        }
    } else {
        // gather: x_new[j,:] = x[perm[j],:] * factor[j]; wave-per-row
        const int gw = (b - NBE) * 4 + w;              // 0..6143
        for (int j = gw; j < NKEEP; j += (K3_BLOCKS - NBE) * 4) {   // 17-18 it
            const int node = perm_i[j];
            const float f  = factor[j];
            float4 v = ((const float4*)(x + (size_t)node * D))[lane];
            v4f o;
            o.x = v.x * f; o.y = v.y * f; o.z = v.z * f; o.w = v.w * f;
            __builtin_nontemporal_store(o, &((v4f*)(out + OUT_X + (size_t)j * D))[lane]);
        }
    }
}

extern "C" void kernel_launch(void* const* d_in, const int* in_sizes, int n_in,
                              void* d_out, int out_size, void* d_ws, size_t ws_size,
                              hipStream_t stream) {
    (void)in_sizes; (void)n_in; (void)out_size; (void)ws_size;

    const float* x  = (const float*)d_in[0];
    const int*   ei = (const int*)d_in[1];
    // d_in[2] (batch) unused: graphs are contiguous so batch[node] = node/NP
    const float* W  = (const float*)d_in[3];
    const float* b  = (const float*)d_in[4];
    float* out = (float*)d_out;

    // Workspace layout (~0.5 MB; ws is poisoned each call -> all re-inited)
    float* wsf      = (float*)d_ws;
    float* h        = wsf;                                // [NTOT]
    int*   new_id   = (int*)(wsf + NTOT);                 // [NTOT]
    int*   perm_i   = (int*)(wsf + 2 * NTOT);             // [NKEEP]
    float* factor   = wsf + 2 * NTOT + NKEEP;             // [NKEEP]

    const int* rows = ei;        // edge_index[0] = sources
    const int* cols = ei + ET;   // edge_index[1] = targets

    hipLaunchKernelGGL(k1_h, dim3(K1_BLOCKS), dim3(256), 0, stream,
                       x, W, h, new_id);
    hipLaunchKernelGGL(k2_graph, dim3(NG), dim3(1024), 0, stream,
                       h, b, rows, cols, perm_i, new_id, factor,
                       out + OUT_PERM, out + OUT_BATCH);
    hipLaunchKernelGGL(k3_gather_edge, dim3(K3_BLOCKS), dim3(256), 0, stream,
                       x, rows, cols, new_id, perm_i, factor, out);
}

// Round 5
// 348.459 us; speedup vs baseline: 1.0059x; 1.0059x over previous
//
#include <hip/hip_runtime.h>
#include <math.h>

// Problem constants (fixed by the reference)
constexpr int NG    = 128;          // graphs
constexpr int NP    = 1024;         // nodes per graph
constexpr int D     = 256;          // feature dim
constexpr int NTOT  = NG * NP;      // 131072 nodes
constexpr int EPG   = NP * 32;      // 32768 edges per graph (contiguous slice)
constexpr int ET    = NTOT * 32;    // 4194304 edges
constexpr int KK    = 820;          // kept per graph
constexpr int KH    = KK / 2;       // 410 kept rows per block-half
constexpr int NKEEP = NG * KK;      // 104960 kept nodes
constexpr int EHALF = EPG / 2;      // 16384 edges per block-half

// Native clang vector type: __builtin_nontemporal_store rejects HIP float4
typedef float v4f __attribute__((ext_vector_type(4)));

// Output layout (flat float32, reference return order)
constexpr long long OUT_X     = 0;
constexpr long long OUT_EI0   = (long long)NKEEP * D;     // 26869760
constexpr long long OUT_EI1   = OUT_EI0 + ET;
constexpr long long OUT_MASK  = OUT_EI0 + 2LL * ET;
constexpr long long OUT_BATCH = OUT_MASK + ET;
constexpr long long OUT_PERM  = OUT_BATCH + NKEEP;        // total 39662592

// ---------------------------------------------------------------------------
// ONE kernel, 256 blocks x 1024 threads. Blocks 2g and 2g+1 each redundantly
// run graph g's full pipeline in LDS (h -> deg -> acc -> score -> bitonic
// top-k -> new_id), then split the epilogue: half h writes gather rows
// [h*410, h*410+410) and edge slice [h*16384, +16384). No grid sync, no
// global intermediates, no workspace. LDS 24 KB -> 1 block/CU, 16 waves.
__global__ __launch_bounds__(1024) void sagpool_fused(
        const float* __restrict__ x,   const float* __restrict__ W,
        const float* __restrict__ bptr,
        const int* __restrict__ rows,  const int* __restrict__ cols,
        float* __restrict__ out) {
    __shared__ float h_lds[NP];             // 4 KB; later aliased as kidx
    __shared__ unsigned long long sk[NP];   // 8 KB; cnt | ul, then sort buffer
    __shared__ float acc[NP];               // 4 KB; later aliased as kfac
    __shared__ float scl[NP];               // 4 KB; scores
    __shared__ int   nid[NP];               // 4 KB; new_id for this graph
    int*   cnt  = (int*)sk;                 // bytes [0, 4K)
    float* ul   = (float*)sk + NP;          // bytes [4K, 8K)
    int*   kidx = (int*)h_lds;              // h dead after score
    float* kfac = acc;                      // acc dead after score

    const int blk  = blockIdx.x;            // 0..255
    const int t    = threadIdx.x;           // 0..1023
    const int w    = t >> 6;                // wave 0..15
    const int lane = t & 63;
    const int g    = blk >> 1;
    const int half = blk & 1;

    cnt[t] = 0;
    nid[t] = -1;

    // -------- Phase A: h[r] = dot(x[g*NP+r,:], W) for ALL 1024 rows --------
    // wave w owns rows [w*64, w*64+64), 4 rows in flight per chunk.
    {
        float4 w4 = ((const float4*)W)[lane];
        const float4* xp = (const float4*)(x + (size_t)g * NP * D);
#pragma unroll
        for (int c = 0; c < 16; ++c) {
            const int r0 = w * 64 + c * 4;
            float4 a0 = xp[(r0 + 0) * 64 + lane];
            float4 a1 = xp[(r0 + 1) * 64 + lane];
            float4 a2 = xp[(r0 + 2) * 64 + lane];
            float4 a3 = xp[(r0 + 3) * 64 + lane];
            float s0 = a0.x * w4.x + a0.y * w4.y + a0.z * w4.z + a0.w * w4.w;
            float s1 = a1.x * w4.x + a1.y * w4.y + a1.z * w4.z + a1.w * w4.w;
            float s2 = a2.x * w4.x + a2.y * w4.y + a2.z * w4.z + a2.w * w4.w;
            float s3 = a3.x * w4.x + a3.y * w4.y + a3.z * w4.z + a3.w * w4.w;
#pragma unroll
            for (int off = 32; off > 0; off >>= 1) {
                s0 += __shfl_down(s0, off, 64);
                s1 += __shfl_down(s1, off, 64);
                s2 += __shfl_down(s2, off, 64);
                s3 += __shfl_down(s3, off, 64);
            }
            if (lane == 0) {
                h_lds[r0]     = s0; h_lds[r0 + 1] = s1;
                h_lds[r0 + 2] = s2; h_lds[r0 + 3] = s3;
            }
        }
    }
    __syncthreads();

    const int4* c4p = (const int4*)(cols + (size_t)g * EPG);
    const int4* r4p = (const int4*)(rows + (size_t)g * EPG);

    // -------- Phase B: degree over all 32768 edges (LDS atomics) -----------
#pragma unroll
    for (int i = t; i < EPG / 4; i += 1024) {        // 8 iters
        int4 c = c4p[i];
        atomicAdd(&cnt[c.x & (NP - 1)], 1);
        atomicAdd(&cnt[c.y & (NP - 1)], 1);
        atomicAdd(&cnt[c.z & (NP - 1)], 1);
        atomicAdd(&cnt[c.w & (NP - 1)], 1);
    }
    __syncthreads();

    const float hv = h_lds[t];
    const float di = rsqrtf((float)(1 + cnt[t]));    // self-loop included
    ul[t]  = di * hv;
    acc[t] = 0.0f;
    __syncthreads();

    // -------- Phase C: acc[c] += u[r] over all edges (LDS atomics) ---------
#pragma unroll
    for (int i = t; i < EPG / 4; i += 1024) {        // 8 iters
        int4 c = c4p[i];
        int4 r = r4p[i];
        atomicAdd(&acc[c.x & (NP - 1)], ul[r.x & (NP - 1)]);
        atomicAdd(&acc[c.y & (NP - 1)], ul[r.y & (NP - 1)]);
        atomicAdd(&acc[c.z & (NP - 1)], ul[r.z & (NP - 1)]);
        atomicAdd(&acc[c.w & (NP - 1)], ul[r.w & (NP - 1)]);
    }
    __syncthreads();

    // -------- Score + register bitonic full sort ---------------------------
    const float score = di * acc[t] + di * di * hv + bptr[0];
    scl[t] = score;

    // sortable key: ascending u64 == (descending score, ascending idx)
    unsigned int fu = __float_as_uint(score);
    unsigned int s  = (fu & 0x80000000u) ? ~fu : (fu | 0x80000000u);
    unsigned long long key = ((unsigned long long)(~s) << 32) | (unsigned int)t;
    // ul reads finished before last barrier; sk is free for sort stages.

    for (int k = 2; k <= NP; k <<= 1) {
        for (int j = k >> 1; j > 0; j >>= 1) {
            unsigned long long other;
            if (j < 64) {
                other = __shfl_xor(key, j, 64);
            } else {
                sk[t] = key;
                __syncthreads();
                other = sk[t ^ j];
                __syncthreads();
            }
            bool take_min = (((t & k) == 0) == ((t & j) == 0));
            bool omin = other < key;
            key = (take_min == omin) ? other : key;
        }
    }
    // sort's internal barriers ordered scl[] writes before the reads below

    // -------- Epilogue bookkeeping (LDS only; half-split outputs) ----------
    if (t < KK) {
        int idx  = (int)(key & 0xFFFFFFFFull);
        nid[idx] = g * KK + t;                       // full new_id map in LDS
        if (t >= half * KH && t < half * KH + KH) {  // this block's 410 rows
            const int l = t - half * KH;
            kidx[l] = idx;
            kfac[l] = tanhf(scl[idx]);
            const int jj = g * KK + t;
            out[OUT_PERM + jj]  = (float)(g * NP + idx);
            out[OUT_BATCH + jj] = (float)g;          // contiguous graphs
        }
    }
    __syncthreads();

    // -------- Phase E1: gather x_new rows (410 per block) ------------------
    for (int l = w; l < KH; l += 16) {               // 25-26 iters per wave
        const int   ni = kidx[l];
        const float f  = kfac[l];
        float4 v = ((const float4*)(x + ((size_t)(g * NP + ni)) * D))[lane];
        v4f o;
        o.x = v.x * f; o.y = v.y * f; o.z = v.z * f; o.w = v.w * f;
        const size_t j = (size_t)g * KK + half * KH + l;
        __builtin_nontemporal_store(o, &((v4f*)(out + OUT_X + j * D))[lane]);
    }

    // -------- Phase E2: edge remap (16384 edges per block) -----------------
    {
        const size_t eoff = (size_t)g * EPG + (size_t)half * EHALF;
        const int4* r4 = (const int4*)(rows + eoff);
        const int4* c4 = (const int4*)(cols + eoff);
        v4f* orr = (v4f*)(out + OUT_EI0  + eoff);
        v4f* occ = (v4f*)(out + OUT_EI1  + eoff);
        v4f* omm = (v4f*)(out + OUT_MASK + eoff);
#pragma unroll
        for (int i = t; i < EHALF / 4; i += 1024) {  // 4 iters
            int4 r = r4[i];
            int4 c = c4[i];
            v4f fr, fc, fm;
            {
                int nr = nid[r.x & (NP - 1)], nc = nid[c.x & (NP - 1)];
                bool m = (nr >= 0) && (nc >= 0);
                fr.x = m ? (float)nr : -1.0f; fc.x = m ? (float)nc : -1.0f; fm.x = m ? 1.0f : 0.0f;
            }
            {
                int nr = nid[r.y & (NP - 1)], nc = nid[c.y & (NP - 1)];
                bool m = (nr >= 0) && (nc >= 0);
                fr.y = m ? (float)nr : -1.0f; fc.y = m ? (float)nc : -1.0f; fm.y = m ? 1.0f : 0.0f;
            }
            {
                int nr = nid[r.z & (NP - 1)], nc = nid[c.z & (NP - 1)];
                bool m = (nr >= 0) && (nc >= 0);
                fr.z = m ? (float)nr : -1.0f; fc.z = m ? (float)nc : -1.0f; fm.z = m ? 1.0f : 0.0f;
            }
            {
                int nr = nid[r.w & (NP - 1)], nc = nid[c.w & (NP - 1)];
                bool m = (nr >= 0) && (nc >= 0);
                fr.w = m ? (float)nr : -1.0f; fc.w = m ? (float)nc : -1.0f; fm.w = m ? 1.0f : 0.0f;
            }
            __builtin_nontemporal_store(fr, &orr[i]);
            __builtin_nontemporal_store(fc, &occ[i]);
            __builtin_nontemporal_store(fm, &omm[i]);
        }
    }
}

extern "C" void kernel_launch(void* const* d_in, const int* in_sizes, int n_in,
                              void* d_out, int out_size, void* d_ws, size_t ws_size,
                              hipStream_t stream) {
    (void)in_sizes; (void)n_in; (void)out_size; (void)d_ws; (void)ws_size;

    const float* x  = (const float*)d_in[0];
    const int*   ei = (const int*)d_in[1];
    // d_in[2] (batch) unused: graphs are contiguous so batch[node] = node/NP
    const float* W  = (const float*)d_in[3];
    const float* b  = (const float*)d_in[4];
    float* out = (float*)d_out;

    const int* rows = ei;        // edge_index[0] = sources
    const int* cols = ei + ET;   // edge_index[1] = targets

    // Single dispatch; zero workspace, zero global intermediates.
    hipLaunchKernelGGL(sagpool_fused, dim3(2 * NG), dim3(1024), 0, stream,
                       x, W, b, rows, cols, out);
}